// Round 8
// baseline (106.816 us; speedup 1.0000x reference)
//
#include <hip/hip_runtime.h>
#include <hip/hip_bf16.h>

// ---------------- problem constants ----------------
#define S_LEN 4096
#define IN_DIM 768
#define D_DIM 512
#define N_HEADS 8
#define H_DIM 64
#define TSE_DIM 1536   // 3*DIM

typedef __attribute__((ext_vector_type(8))) short frag8;   // 8 bf16 = 4 VGPRs
typedef __attribute__((ext_vector_type(4))) float f32x4;

__device__ __forceinline__ unsigned short f2bfbits(float f) {
    unsigned int u = __float_as_uint(f);
    unsigned int r = (u + 0x7FFFu + ((u >> 16) & 1u)) >> 16;
    return (unsigned short)r;
}
__device__ __forceinline__ float bf2f(unsigned short b) {
    return __uint_as_float(((unsigned int)b) << 16);
}

// async global->LDS, 16B per lane. LDS dest wave-uniform; HW adds lane*16.
__device__ __forceinline__ void gload_lds16(const void* g, void* l) {
    __builtin_amdgcn_global_load_lds(
        (const __attribute__((address_space(1))) unsigned int*)g,
        (__attribute__((address_space(3))) unsigned int*)l,
        16, 0, 0);
}

// ---------------- prep: x->bf16 + 3 weight transpose-converts (R5 version) ----------------
// block ranges: [0,3072) x-cvt | [3072,3456) W_in | [3456,4224) W_tse | [4224,4480) W_out
__global__ __launch_bounds__(256) void prep_kernel(
        const float4* __restrict__ x4, ushort4* __restrict__ xb4,
        const float* __restrict__ W_in,  unsigned short* __restrict__ WinT,
        const float* __restrict__ W_tse, unsigned short* __restrict__ WtseT,
        const float* __restrict__ W_out, unsigned short* __restrict__ WoutT) {
    __shared__ float tile[32][33];
    int b = blockIdx.x;
    if (b < 3072) {
        int i = b * 256 + threadIdx.x;
        float4 v = x4[i];
        ushort4 o;
        o.x = f2bfbits(v.x); o.y = f2bfbits(v.y);
        o.z = f2bfbits(v.z); o.w = f2bfbits(v.w);
        xb4[i] = o;
        return;
    }
    const float* in; unsigned short* out; int K, N, t;
    if (b < 3456)      { t = b - 3072; in = W_in;  out = WinT;  K = IN_DIM; N = D_DIM;  }
    else if (b < 4224) { t = b - 3456; in = W_tse; out = WtseT; K = D_DIM;  N = TSE_DIM;}
    else               { t = b - 4224; in = W_out; out = WoutT; K = D_DIM;  N = D_DIM;  }
    int ktiles = K / 32;
    int kb = (t % ktiles) * 32, nb = (t / ktiles) * 32;
    int tx = threadIdx.x & 31, ty = threadIdx.x >> 5;
    #pragma unroll
    for (int r = ty; r < 32; r += 8)
        tile[r][tx] = in[(size_t)(kb + r) * N + nb + tx];
    __syncthreads();
    #pragma unroll
    for (int r = ty; r < 32; r += 8)
        out[(size_t)(nb + r) * K + kb + tx] = f2bfbits(tile[tx][r]);
}

// ---------------- bf16 NT-GEMM, 64x64 tile, 2-phase double-buffered (R5, proven) --------
template<bool OUT_BF16, bool BIAS>
__global__ __launch_bounds__(256) void gemm_nt(
        const unsigned short* __restrict__ A,
        const unsigned short* __restrict__ Bt,
        const float* __restrict__ bias,
        void* __restrict__ C,
        int M, int N, int K) {
    __shared__ __align__(16) unsigned short As[2][64 * 32];
    __shared__ __align__(16) unsigned short Bs[2][64 * 32];

    const int bm = blockIdx.x * 64;
    const int bn = blockIdx.y * 64;
    const int lane = threadIdx.x & 63;
    const int wave = threadIdx.x >> 6;
    const int wr = wave >> 1;
    const int wc = wave & 1;
    const int fr = lane & 15;
    const int fg = lane >> 4;

    const int srow = lane >> 2;
    const int scol = (lane & 3) * 8;

    const unsigned short* agp = A  + (size_t)(bm + wave * 16 + srow) * K + scol;
    const unsigned short* bgp = Bt + (size_t)(bn + wave * 16 + srow) * K + scol;
    unsigned short* alp0 = &As[0][wave * 512];
    unsigned short* blp0 = &Bs[0][wave * 512];
    unsigned short* alp1 = &As[1][wave * 512];
    unsigned short* blp1 = &Bs[1][wave * 512];

    f32x4 acc[2][2];
    #pragma unroll
    for (int mi = 0; mi < 2; ++mi)
        #pragma unroll
        for (int ni = 0; ni < 2; ++ni)
            acc[mi][ni] = (f32x4)(0.f);

    const int nt = K >> 5;

    gload_lds16(agp, alp0);
    gload_lds16(bgp, blp0);
    __syncthreads();

    int cur = 0;
    for (int kt = 0; kt + 1 < nt; ++kt) {
        const int ko = (kt + 1) << 5;
        gload_lds16(agp + ko, cur ? alp0 : alp1);
        gload_lds16(bgp + ko, cur ? blp0 : blp1);

        frag8 a[2], b[2];
        #pragma unroll
        for (int mi = 0; mi < 2; ++mi)
            a[mi] = *(const frag8*)&As[cur][(wr * 32 + mi * 16 + fr) * 32 + fg * 8];
        #pragma unroll
        for (int ni = 0; ni < 2; ++ni)
            b[ni] = *(const frag8*)&Bs[cur][(wc * 32 + ni * 16 + fr) * 32 + fg * 8];
        #pragma unroll
        for (int mi = 0; mi < 2; ++mi)
            #pragma unroll
            for (int ni = 0; ni < 2; ++ni)
                acc[mi][ni] = __builtin_amdgcn_mfma_f32_16x16x32_bf16(
                        a[mi], b[ni], acc[mi][ni], 0, 0, 0);

        __syncthreads();
        cur ^= 1;
    }

    {   // epilogue tile
        frag8 a[2], b[2];
        #pragma unroll
        for (int mi = 0; mi < 2; ++mi)
            a[mi] = *(const frag8*)&As[cur][(wr * 32 + mi * 16 + fr) * 32 + fg * 8];
        #pragma unroll
        for (int ni = 0; ni < 2; ++ni)
            b[ni] = *(const frag8*)&Bs[cur][(wc * 32 + ni * 16 + fr) * 32 + fg * 8];
        #pragma unroll
        for (int mi = 0; mi < 2; ++mi)
            #pragma unroll
            for (int ni = 0; ni < 2; ++ni)
                acc[mi][ni] = __builtin_amdgcn_mfma_f32_16x16x32_bf16(
                        a[mi], b[ni], acc[mi][ni], 0, 0, 0);
    }

    #pragma unroll
    for (int mi = 0; mi < 2; ++mi) {
        int grow = bm + wr * 32 + mi * 16 + fg * 4;
        #pragma unroll
        for (int ni = 0; ni < 2; ++ni) {
            int gcol = bn + wc * 32 + ni * 16 + fr;
            float bv = BIAS ? bias[gcol] : 0.f;
            #pragma unroll
            for (int r = 0; r < 4; ++r) {
                float v = acc[mi][ni][r] + bv;
                if (OUT_BF16)
                    ((unsigned short*)C)[(size_t)(grow + r) * N + gcol] = f2bfbits(v);
                else
                    ((float*)C)[(size_t)(grow + r) * N + gcol] = v;
            }
        }
    }
}

// ---------------- fused: attention (phase 1, into LDS) + GEMM3 (phase 2) ----------------
// out[bm..bm+64) x [bn..bn+64) = attn(tse)[rows] @ WoutT^T + b_out, fp32.
// A never touches global memory; XOR-swizzled LDS (byte ^= (row&7)<<4) keeps the
// row-strided a-frag ds_read at 2-way bank aliasing (free, m136).
__global__ __launch_bounds__(256) void gemm3_attn(
        const unsigned short* __restrict__ tse,
        const unsigned short* __restrict__ Bt,     // WoutT [512][512] bf16
        const float* __restrict__ bias,            // b_out
        float* __restrict__ C) {
    __shared__ __align__(16) unsigned short Ab[64 * 512];   // 64 KB, swizzled
    __shared__ __align__(16) unsigned short Bs[2][64 * 32]; // 8 KB dbuf

    const int bm = blockIdx.x * 64;
    const int bn = blockIdx.y * 64;
    const int lane = threadIdx.x & 63;
    const int wave = threadIdx.x >> 6;
    const int wr = wave >> 1;
    const int wc = wave & 1;
    const int fr = lane & 15;
    const int fg = lane >> 4;
    const int srow = lane >> 2;
    const int scol = (lane & 3) * 8;

    // ---- phase 1: attention for rows [bm + wave*16, +16), lane = h*8 + d-chunk ----
    const int off = (lane >> 3) * H_DIM + (lane & 7) * 8;
    for (int ir = 0; ir < 16; ++ir) {
        const int s = bm + wave * 16 + ir;

        float qf[8];
        {
            frag8 q = *(const frag8*)(tse + (size_t)s * TSE_DIM + off);
            #pragma unroll
            for (int i = 0; i < 8; ++i) qf[i] = bf2f((unsigned short)q[i]);
        }

        float sc[7];
        #pragma unroll
        for (int j = 0; j < 7; ++j) {
            int t = s + (j - 3) * 8;
            bool valid = (t >= 0) && (t < S_LEN);
            float p = 0.f;
            if (valid) {
                frag8 k = *(const frag8*)(tse + (size_t)t * TSE_DIM + D_DIM + off);
                #pragma unroll
                for (int i = 0; i < 8; ++i) p += qf[i] * bf2f((unsigned short)k[i]);
            }
            p += __shfl_xor(p, 1, 64);
            p += __shfl_xor(p, 2, 64);
            p += __shfl_xor(p, 4, 64);
            sc[j] = valid ? p * 0.125f : -__builtin_inff();
        }

        float m = sc[0];
        #pragma unroll
        for (int j = 1; j < 7; ++j) m = fmaxf(m, sc[j]);

        float w[7], denom = 0.f;
        #pragma unroll
        for (int j = 0; j < 7; ++j) {
            w[j] = (sc[j] == -__builtin_inff()) ? 0.f : __expf(sc[j] - m);
            denom += w[j];
        }
        const float inv = 1.f / denom;

        float of[8];
        #pragma unroll
        for (int i = 0; i < 8; ++i) of[i] = 0.f;
        #pragma unroll
        for (int j = 0; j < 7; ++j) {
            int t = s + (j - 3) * 8;
            if (t >= 0 && t < S_LEN) {
                frag8 v = *(const frag8*)(tse + (size_t)t * TSE_DIM + 2 * D_DIM + off);
                #pragma unroll
                for (int i = 0; i < 8; ++i) of[i] += w[j] * bf2f((unsigned short)v[i]);
            }
        }

        frag8 o;
        #pragma unroll
        for (int i = 0; i < 8; ++i) o[i] = (short)f2bfbits(of[i] * inv);

        const int lrow = wave * 16 + ir;
        *(frag8*)((char*)Ab + (size_t)lrow * 1024 + ((off * 2) ^ ((lrow & 7) << 4))) = o;
    }

    // ---- phase 2: K-loop, A from LDS, B double-buffer-staged ----
    const unsigned short* bgp = Bt + (size_t)(bn + wave * 16 + srow) * D_DIM + scol;
    unsigned short* blp0 = &Bs[0][wave * 512];
    unsigned short* blp1 = &Bs[1][wave * 512];

    gload_lds16(bgp, blp0);
    __syncthreads();   // attn rows visible to all waves + B tile 0 staged

    f32x4 acc[2][2];
    #pragma unroll
    for (int mi = 0; mi < 2; ++mi)
        #pragma unroll
        for (int ni = 0; ni < 2; ++ni)
            acc[mi][ni] = (f32x4)(0.f);

    const int nt = D_DIM >> 5;   // 16
    const char* abase = (const char*)Ab;
    int cur = 0;
    for (int kt = 0; kt < nt; ++kt) {
        if (kt + 1 < nt)
            gload_lds16(bgp + ((kt + 1) << 5), cur ? blp0 : blp1);

        frag8 a[2], b[2];
        #pragma unroll
        for (int mi = 0; mi < 2; ++mi) {
            const int row = wr * 32 + mi * 16 + fr;
            a[mi] = *(const frag8*)(abase + (size_t)row * 1024 +
                                    ((kt * 64 + fg * 16) ^ ((fr & 7) << 4)));
        }
        #pragma unroll
        for (int ni = 0; ni < 2; ++ni)
            b[ni] = *(const frag8*)&Bs[cur][(wc * 32 + ni * 16 + fr) * 32 + fg * 8];
        #pragma unroll
        for (int mi = 0; mi < 2; ++mi)
            #pragma unroll
            for (int ni = 0; ni < 2; ++ni)
                acc[mi][ni] = __builtin_amdgcn_mfma_f32_16x16x32_bf16(
                        a[mi], b[ni], acc[mi][ni], 0, 0, 0);

        if (kt + 1 < nt) {
            __syncthreads();
            cur ^= 1;
        }
    }

    // epilogue: fp32 + b_out
    #pragma unroll
    for (int mi = 0; mi < 2; ++mi) {
        int grow = bm + wr * 32 + mi * 16 + fg * 4;
        #pragma unroll
        for (int ni = 0; ni < 2; ++ni) {
            int gcol = bn + wc * 32 + ni * 16 + fr;
            float bv = bias[gcol];
            #pragma unroll
            for (int r = 0; r < 4; ++r)
                C[(size_t)(grow + r) * D_DIM + gcol] = acc[mi][ni][r] + bv;
        }
    }
}

// ---------------- launch ----------------
extern "C" void kernel_launch(void* const* d_in, const int* in_sizes, int n_in,
                              void* d_out, int out_size, void* d_ws, size_t ws_size,
                              hipStream_t stream) {
    (void)in_sizes; (void)n_in; (void)out_size;
    const float* x     = (const float*)d_in[0];
    const float* W_in  = (const float*)d_in[1];
    const float* b_in  = (const float*)d_in[2];
    const float* W_tse = (const float*)d_in[3];
    const float* W_out = (const float*)d_in[4];
    const float* b_out = (const float*)d_in[5];

    char* p = (char*)d_ws;
    unsigned short* xb    = (unsigned short*)p; p += (size_t)S_LEN * IN_DIM * 2;
    unsigned short* WinT  = (unsigned short*)p; p += (size_t)D_DIM * IN_DIM * 2;
    unsigned short* WtseT = (unsigned short*)p; p += (size_t)TSE_DIM * D_DIM * 2;
    unsigned short* WoutT = (unsigned short*)p; p += (size_t)D_DIM * D_DIM * 2;
    unsigned short* h     = (unsigned short*)p; p += (size_t)S_LEN * D_DIM * 2;
    unsigned short* tse   = (unsigned short*)p; p += (size_t)S_LEN * TSE_DIM * 2;
    if ((size_t)(p - (char*)d_ws) > ws_size) return;

    // conversions: 3072 + 384 + 768 + 256 = 4480 blocks
    prep_kernel<<<4480, 256, 0, stream>>>(
            (const float4*)x, (ushort4*)xb, W_in, WinT, W_tse, WtseT, W_out, WoutT);

    // h = x @ W_in + b_in   (bf16 out)  -- grid (64,8)
    gemm_nt<true, true><<<dim3(S_LEN / 64, D_DIM / 64), 256, 0, stream>>>(
            xb, WinT, b_in, h, S_LEN, D_DIM, IN_DIM);
    // tse = h @ W_tse       (bf16 out)  -- grid (64,24)
    gemm_nt<true, false><<<dim3(S_LEN / 64, TSE_DIM / 64), 256, 0, stream>>>(
            h, WtseT, nullptr, tse, S_LEN, TSE_DIM, D_DIM);
    // out = attn(tse) @ W_out + b_out   (fused, fp32 out) -- grid (64,8)
    gemm3_attn<<<dim3(S_LEN / 64, D_DIM / 64), 256, 0, stream>>>(
            tse, WoutT, b_out, (float*)d_out);
}

// Round 9
// 55.372 us; speedup vs baseline: 1.9291x; 1.9291x over previous
//
#include <hip/hip_runtime.h>
#include <hip/hip_bf16.h>

// ---------------- problem constants ----------------
#define S_LEN 4096
#define IN_DIM 768
#define D_DIM 512
#define N_HEADS 8
#define H_DIM 64
#define TSE_DIM 1536   // 3*DIM

typedef __attribute__((ext_vector_type(8))) short frag8;   // 8 bf16 = 4 VGPRs
typedef __attribute__((ext_vector_type(4))) float f32x4;

__device__ __forceinline__ unsigned short f2bfbits(float f) {
    unsigned int u = __float_as_uint(f);
    unsigned int r = (u + 0x7FFFu + ((u >> 16) & 1u)) >> 16;
    return (unsigned short)r;
}
__device__ __forceinline__ float bf2f(unsigned short b) {
    return __uint_as_float(((unsigned int)b) << 16);
}

// async global->LDS, 16B per lane. LDS dest wave-uniform; HW adds lane*16.
__device__ __forceinline__ void gload_lds16(const void* g, void* l) {
    __builtin_amdgcn_global_load_lds(
        (const __attribute__((address_space(1))) unsigned int*)g,
        (__attribute__((address_space(3))) unsigned int*)l,
        16, 0, 0);
}

// ---------------- prep: x->bf16 + 3 weight transpose-converts ----------------
// block ranges: [0,3072) x-cvt | [3072,3456) W_in | [3456,4224) W_tse | [4224,4480) W_out
__global__ __launch_bounds__(256) void prep_kernel(
        const float4* __restrict__ x4, ushort4* __restrict__ xb4,
        const float* __restrict__ W_in,  unsigned short* __restrict__ WinT,
        const float* __restrict__ W_tse, unsigned short* __restrict__ WtseT,
        const float* __restrict__ W_out, unsigned short* __restrict__ WoutT) {
    __shared__ float tile[32][33];
    int b = blockIdx.x;
    if (b < 3072) {
        int i = b * 256 + threadIdx.x;
        float4 v = x4[i];
        ushort4 o;
        o.x = f2bfbits(v.x); o.y = f2bfbits(v.y);
        o.z = f2bfbits(v.z); o.w = f2bfbits(v.w);
        xb4[i] = o;
        return;
    }
    const float* in; unsigned short* out; int K, N, t;
    if (b < 3456)      { t = b - 3072; in = W_in;  out = WinT;  K = IN_DIM; N = D_DIM;  }
    else if (b < 4224) { t = b - 3456; in = W_tse; out = WtseT; K = D_DIM;  N = TSE_DIM;}
    else               { t = b - 4224; in = W_out; out = WoutT; K = D_DIM;  N = D_DIM;  }
    int ktiles = K / 32;
    int kb = (t % ktiles) * 32, nb = (t / ktiles) * 32;
    int tx = threadIdx.x & 31, ty = threadIdx.x >> 5;
    #pragma unroll
    for (int r = ty; r < 32; r += 8)
        tile[r][tx] = in[(size_t)(kb + r) * N + nb + tx];
    __syncthreads();
    #pragma unroll
    for (int r = ty; r < 32; r += 8)
        out[(size_t)(nb + r) * K + kb + tx] = f2bfbits(tile[tx][r]);
}

// ---------------- bf16 NT-GEMM, (MF*32)x(NF*32) tile, 2-phase double-buffered --------
// C[M][N] = A[M][K] * Bt[N][K]^T (+bias). BK=32, 4 waves (2x2); wave = (MF*16)x(NF*16)
// = MF x NF frags of 16x16x32. Staging: global_load_lds w16, linear LDS 1024B chunks.
template<int MF, int NF, bool OUT_BF16, bool BIAS>
__global__ __launch_bounds__(256) void gemm_nt(
        const unsigned short* __restrict__ A,
        const unsigned short* __restrict__ Bt,
        const float* __restrict__ bias,
        void* __restrict__ C,
        int M, int N, int K) {
    constexpr int BM = MF * 32, BN = NF * 32;
    constexpr int AI = MF / 2;           // A-chunk stage issues per wave
    constexpr int BI = NF / 2;           // B-chunk stage issues per wave
    __shared__ __align__(16) unsigned short As[2][BM * 32];
    __shared__ __align__(16) unsigned short Bs[2][BN * 32];

    const int bm = blockIdx.x * BM;
    const int bn = blockIdx.y * BN;
    const int lane = threadIdx.x & 63;
    const int wave = threadIdx.x >> 6;
    const int wr = wave >> 1;            // 0..1
    const int wc = wave & 1;             // 0..1
    const int fr = lane & 15;
    const int fg = lane >> 4;            // k-group 0..3

    const int srow = lane >> 2;          // staging: chunk = 16 rows x 32 cols = 1024B
    const int scol = (lane & 3) * 8;

    const unsigned short* agp[AI];
    const unsigned short* bgp[BI];
    #pragma unroll
    for (int r = 0; r < AI; ++r)
        agp[r] = A + (size_t)(bm + (wave * AI + r) * 16 + srow) * K + scol;
    #pragma unroll
    for (int r = 0; r < BI; ++r)
        bgp[r] = Bt + (size_t)(bn + (wave * BI + r) * 16 + srow) * K + scol;

    f32x4 acc[MF][NF];
    #pragma unroll
    for (int mi = 0; mi < MF; ++mi)
        #pragma unroll
        for (int ni = 0; ni < NF; ++ni)
            acc[mi][ni] = (f32x4)(0.f);

    const int nt = K >> 5;

    // prologue: stage tile 0 into buf 0
    #pragma unroll
    for (int r = 0; r < AI; ++r) gload_lds16(agp[r], &As[0][(wave * AI + r) * 512]);
    #pragma unroll
    for (int r = 0; r < BI; ++r) gload_lds16(bgp[r], &Bs[0][(wave * BI + r) * 512]);
    __syncthreads();

    int cur = 0;
    for (int kt = 0; kt + 1 < nt; ++kt) {
        const int ko = (kt + 1) << 5;
        const int nb = cur ^ 1;
        #pragma unroll
        for (int r = 0; r < AI; ++r)
            gload_lds16(agp[r] + ko, &As[nb][(wave * AI + r) * 512]);
        #pragma unroll
        for (int r = 0; r < BI; ++r)
            gload_lds16(bgp[r] + ko, &Bs[nb][(wave * BI + r) * 512]);

        frag8 a[MF], b[NF];
        #pragma unroll
        for (int mi = 0; mi < MF; ++mi)
            a[mi] = *(const frag8*)&As[cur][(wr * (BM / 2) + mi * 16 + fr) * 32 + fg * 8];
        #pragma unroll
        for (int ni = 0; ni < NF; ++ni)
            b[ni] = *(const frag8*)&Bs[cur][(wc * (BN / 2) + ni * 16 + fr) * 32 + fg * 8];
        #pragma unroll
        for (int mi = 0; mi < MF; ++mi)
            #pragma unroll
            for (int ni = 0; ni < NF; ++ni)
                acc[mi][ni] = __builtin_amdgcn_mfma_f32_16x16x32_bf16(
                        a[mi], b[ni], acc[mi][ni], 0, 0, 0);

        __syncthreads();
        cur ^= 1;
    }

    {   // epilogue tile (no prefetch)
        frag8 a[MF], b[NF];
        #pragma unroll
        for (int mi = 0; mi < MF; ++mi)
            a[mi] = *(const frag8*)&As[cur][(wr * (BM / 2) + mi * 16 + fr) * 32 + fg * 8];
        #pragma unroll
        for (int ni = 0; ni < NF; ++ni)
            b[ni] = *(const frag8*)&Bs[cur][(wc * (BN / 2) + ni * 16 + fr) * 32 + fg * 8];
        #pragma unroll
        for (int mi = 0; mi < MF; ++mi)
            #pragma unroll
            for (int ni = 0; ni < NF; ++ni)
                acc[mi][ni] = __builtin_amdgcn_mfma_f32_16x16x32_bf16(
                        a[mi], b[ni], acc[mi][ni], 0, 0, 0);
    }

    // C/D layout col=lane&15, row=(lane>>4)*4+reg  [HW-verified m89/m91]
    #pragma unroll
    for (int mi = 0; mi < MF; ++mi) {
        int grow = bm + wr * (BM / 2) + mi * 16 + fg * 4;
        #pragma unroll
        for (int ni = 0; ni < NF; ++ni) {
            int gcol = bn + wc * (BN / 2) + ni * 16 + fr;
            float bv = BIAS ? bias[gcol] : 0.f;
            #pragma unroll
            for (int r = 0; r < 4; ++r) {
                float v = acc[mi][ni][r] + bv;
                if (OUT_BF16)
                    ((unsigned short*)C)[(size_t)(grow + r) * N + gcol] = f2bfbits(v);
                else
                    ((float*)C)[(size_t)(grow + r) * N + gcol] = v;
            }
        }
    }
}

// ---------------- dilated attention: wave <-> s, lane = h*8 + d-chunk ----------------
__global__ __launch_bounds__(256) void attn_kernel(
        const unsigned short* __restrict__ tse, unsigned short* __restrict__ out) {
    const int s    = blockIdx.x * 4 + (threadIdx.x >> 6);
    const int lane = threadIdx.x & 63;
    const int off  = (lane >> 3) * H_DIM + (lane & 7) * 8;   // h*64 + d8*8

    float qf[8];
    {
        frag8 q = *(const frag8*)(tse + (size_t)s * TSE_DIM + off);
        #pragma unroll
        for (int i = 0; i < 8; ++i) qf[i] = bf2f((unsigned short)q[i]);
    }

    float sc[7];
    #pragma unroll
    for (int j = 0; j < 7; ++j) {
        int t = s + (j - 3) * 8;
        bool valid = (t >= 0) && (t < S_LEN);
        float p = 0.f;
        if (valid) {
            frag8 k = *(const frag8*)(tse + (size_t)t * TSE_DIM + D_DIM + off);
            #pragma unroll
            for (int i = 0; i < 8; ++i) p += qf[i] * bf2f((unsigned short)k[i]);
        }
        p += __shfl_xor(p, 1, 64);
        p += __shfl_xor(p, 2, 64);
        p += __shfl_xor(p, 4, 64);
        sc[j] = valid ? p * 0.125f : -__builtin_inff();
    }

    float m = sc[0];
    #pragma unroll
    for (int j = 1; j < 7; ++j) m = fmaxf(m, sc[j]);

    float w[7], denom = 0.f;
    #pragma unroll
    for (int j = 0; j < 7; ++j) {
        w[j] = (sc[j] == -__builtin_inff()) ? 0.f : __expf(sc[j] - m);
        denom += w[j];
    }
    const float inv = 1.f / denom;

    float of[8];
    #pragma unroll
    for (int i = 0; i < 8; ++i) of[i] = 0.f;
    #pragma unroll
    for (int j = 0; j < 7; ++j) {
        int t = s + (j - 3) * 8;
        if (t >= 0 && t < S_LEN) {
            frag8 v = *(const frag8*)(tse + (size_t)t * TSE_DIM + 2 * D_DIM + off);
            #pragma unroll
            for (int i = 0; i < 8; ++i) of[i] += w[j] * bf2f((unsigned short)v[i]);
        }
    }

    frag8 o;
    #pragma unroll
    for (int i = 0; i < 8; ++i) o[i] = (short)f2bfbits(of[i] * inv);
    *(frag8*)(out + (size_t)s * D_DIM + off) = o;
}

// ---------------- launch ----------------
extern "C" void kernel_launch(void* const* d_in, const int* in_sizes, int n_in,
                              void* d_out, int out_size, void* d_ws, size_t ws_size,
                              hipStream_t stream) {
    (void)in_sizes; (void)n_in; (void)out_size;
    const float* x     = (const float*)d_in[0];
    const float* W_in  = (const float*)d_in[1];
    const float* b_in  = (const float*)d_in[2];
    const float* W_tse = (const float*)d_in[3];
    const float* W_out = (const float*)d_in[4];
    const float* b_out = (const float*)d_in[5];

    char* p = (char*)d_ws;
    unsigned short* xb    = (unsigned short*)p; p += (size_t)S_LEN * IN_DIM * 2;
    unsigned short* WinT  = (unsigned short*)p; p += (size_t)D_DIM * IN_DIM * 2;
    unsigned short* WtseT = (unsigned short*)p; p += (size_t)TSE_DIM * D_DIM * 2;
    unsigned short* WoutT = (unsigned short*)p; p += (size_t)D_DIM * D_DIM * 2;
    unsigned short* h     = (unsigned short*)p; p += (size_t)S_LEN * D_DIM * 2;
    unsigned short* tse   = (unsigned short*)p; p += (size_t)S_LEN * TSE_DIM * 2;
    unsigned short* attn  = (unsigned short*)p; p += (size_t)S_LEN * D_DIM * 2;
    if ((size_t)(p - (char*)d_ws) > ws_size) return;

    // conversions: 3072 + 384 + 768 + 256 = 4480 blocks
    prep_kernel<<<4480, 256, 0, stream>>>(
            (const float4*)x, (ushort4*)xb, W_in, WinT, W_tse, WtseT, W_out, WoutT);

    // h = x @ W_in + b_in   (bf16 out)  -- 64x64, grid (64,8)=512 blocks, 2/CU
    gemm_nt<2, 2, true, true><<<dim3(S_LEN / 64, D_DIM / 64), 256, 0, stream>>>(
            xb, WinT, b_in, h, S_LEN, D_DIM, IN_DIM);
    // tse = h @ W_tse       (bf16 out)  -- 128x64, grid (32,24)=768 blocks, 3/CU
    gemm_nt<4, 2, true, false><<<dim3(S_LEN / 128, TSE_DIM / 64), 256, 0, stream>>>(
            h, WtseT, nullptr, tse, S_LEN, TSE_DIM, D_DIM);
    // dilated attention     (bf16 out), wave per s
    attn_kernel<<<S_LEN / 4, 256, 0, stream>>>(tse, attn);
    // out = attn @ W_out + b_out  (fp32 out -> d_out)  -- 64x64, grid (64,8)
    gemm_nt<2, 2, false, true><<<dim3(S_LEN / 64, D_DIM / 64), 256, 0, stream>>>(
            attn, WoutT, b_out, (float*)d_out, S_LEN, D_DIM, D_DIM);
}